// Round 9
// baseline (856.662 us; speedup 1.0000x reference)
//
#include <hip/hip_runtime.h>
#include <hip/hip_bf16.h>

#define Vn 25000
#define En 100000
#define NODE_IN 74
#define EDGE_IN 12
#define OUTD 64
#define EHID 128
#define NUM_STEPS 6

typedef __attribute__((ext_vector_type(8))) _Float16 half8;
typedef __attribute__((ext_vector_type(4))) float floatx4;

// h[v,o] = relu(node[v,:] @ Wp + bp)   [V,74]@[74,64]  (all fp32)
__global__ void proj_kernel(const float* __restrict__ node,
                            const float* __restrict__ Wp,
                            const float* __restrict__ bp,
                            float* __restrict__ h) {
  __shared__ float nf[NODE_IN];
  int v = blockIdx.x;
  int o = threadIdx.x;  // 64
  for (int i = o; i < NODE_IN; i += 64) nf[i] = node[(size_t)v * NODE_IN + i];
  __syncthreads();
  float acc = bp[o];
  for (int i = 0; i < NODE_IN; ++i) acc = fmaf(nf[i], Wp[i * OUTD + o], acc);
  h[(size_t)v * OUTD + o] = fmaxf(acc, 0.0f);
}

// f[e,k] = relu(edge[e,:] @ We1 + be1)   [E,12]@[12,128] fp32, stored f16
__global__ void edge_kernel(const float* __restrict__ ef,
                            const float* __restrict__ We1,
                            const float* __restrict__ be1,
                            _Float16* __restrict__ f) {
  __shared__ float es[EDGE_IN];
  int e = blockIdx.x;
  int k = threadIdx.x;  // 128
  if (k < EDGE_IN) es[k] = ef[(size_t)e * EDGE_IN + k];
  __syncthreads();
  float acc = be1[k];
  for (int j = 0; j < EDGE_IN; ++j) acc = fmaf(es[j], We1[j * EHID + k], acc);
  f[(size_t)e * EHID + k] = (_Float16)fmaxf(acc, 0.0f);
}

// SSTEP-contiguous + bank-swizzled B layout (f16) — unchanged from r7/r8.
// Logical index: g = step*2048 + c*512 + l15*32 + quad*8 + j, step = i*4+s,
// value = f16(We2[k = s*32+quad*8+j][col = i*64 + c*16 + l15]).
// Stored at step*2048 + (eidx ^ ((eidx>>6 & 3) << 3))  (quad ^= l15[2:1]).
__global__ void w2r_kernel(const float* __restrict__ We2,
                           _Float16* __restrict__ w2s) {
  int g = blockIdx.x * 256 + threadIdx.x;  // < 524288 (logical index)
  int j = g & 7;
  int quad = (g >> 3) & 3;
  int l15 = (g >> 5) & 15;
  int c = (g >> 9) & 3;
  int step = g >> 11;     // 0..255
  int s = step & 3;
  int i = step >> 2;
  int k = s * 32 + quad * 8 + j;
  int col = i * 64 + c * 16 + l15;
  int eidx = g & 2047;
  int estore = eidx ^ (((eidx >> 6) & 3) << 3);
  w2s[((size_t)step << 11) | estore] = (_Float16)We2[(size_t)k * (OUTD * OUTD) + col];
}

#define GLOAD_LDS(gp, lp)                                                     \
  __builtin_amdgcn_global_load_lds(                                           \
      (const __attribute__((address_space(1))) void*)(gp),                    \
      (__attribute__((address_space(3))) void*)(lp), 16, 0, 0)

// Fused per-step message kernel: ONE WAVE PER 64-EDGE TILE, full i-range.
// acc[4][4] holds the complete [64e][64o] tile -> no cross-wave reduce, no
// barriers, fully independent waves (9 LDS-resident 1-wave blocks/CU).
// B streams global_load_lds -> wave-private 2-slot LDS ring -> registers one
// KSTEP ahead (P/Q). Race-free order per KSTEP (proven r7/r8): lgkmcnt(0)
// drains the slot's ds_reads before the re-stage DMA is issued; vmcnt(4)
// (in-order retirement) guarantees the chunk read this KSTEP has landed.
__global__ __launch_bounds__(64, 2) void msg_kernel(
    const float* __restrict__ h,
    const _Float16* __restrict__ f,
    const _Float16* __restrict__ w2s,
    const int* __restrict__ src,
    const int* __restrict__ dst,
    const float* __restrict__ be2,
    float* __restrict__ agg) {
  // [0,8192): h16[64i][64e] f16 (this tile, transposed); [8192,16384): ring.
  __shared__ __align__(16) char smem_raw[16384];
  __shared__ int s_dst[64];

  _Float16* h16 = (_Float16*)smem_raw;
  char* ring = smem_raw + 8192;

  const int lane = threadIdx.x;
  const int quad = lane >> 4;
  const int l15 = lane & 15;
  const int e0 = blockIdx.x * 64;

  // dst + h-gather/transpose for this wave's tile (lane e owns edge e0+e)
  {
    int eg = e0 + lane;
    s_dst[lane] = (eg < En) ? dst[eg] : -1;
    int sv = (eg < En) ? src[eg] : 0;
    const float4* hp = reinterpret_cast<const float4*>(h + (size_t)sv * OUTD);
#pragma unroll
    for (int c = 0; c < 16; ++c) {
      float4 v = hp[c];
      h16[(c * 4 + 0) * 64 + lane] = (_Float16)v.x;
      h16[(c * 4 + 1) * 64 + lane] = (_Float16)v.y;
      h16[(c * 4 + 2) * 64 + lane] = (_Float16)v.z;
      h16[(c * 4 + 3) * 64 + lane] = (_Float16)v.w;
    }
  }

  // A-fragments (f16): F rows for 4 row-tiles x 4 K-steps (i-invariant).
  half8 afr[4][4];
#pragma unroll
  for (int t = 0; t < 4; ++t) {
    int e = e0 + t * 16 + l15;
    if (e >= En) e = En - 1;  // clamped rows suppressed at scatter
    const _Float16* fr = f + (size_t)e * EHID + quad * 8;
#pragma unroll
    for (int s = 0; s < 4; ++s)
      afr[t][s] = *reinterpret_cast<const half8*>(fr + s * 32);
  }

  floatx4 acc[4][4];  // [row-tile t][col-stripe c] — FULL i-sum
  const floatx4 zero4 = (floatx4){0.f, 0.f, 0.f, 0.f};
#pragma unroll
  for (int t = 0; t < 4; ++t)
#pragma unroll
    for (int c = 0; c < 4; ++c) acc[t][c] = zero4;

  const char* w2b = (const char*)w2s;
  // swizzled per-lane byte offset within a 4KB chunk (stripe c adds 1024)
  const int roff = l15 * 64 + ((quad ^ ((l15 >> 1) & 3)) << 4);
  const char* sp0 = ring + roff;
  const char* sp1 = ring + 4096 + roff;

#define STAGE(GS, SLOT)                                                       \
  {                                                                           \
    const char* gp_ = w2b + (size_t)(GS) * 4096 + lane * 16;                  \
    char* lp_ = ring + (SLOT) * 4096;                                         \
    GLOAD_LDS(gp_, lp_);                                                      \
    GLOAD_LDS(gp_ + 1024, lp_ + 1024);                                        \
    GLOAD_LDS(gp_ + 2048, lp_ + 2048);                                        \
    GLOAD_LDS(gp_ + 3072, lp_ + 3072);                                        \
  }

#define VM4 asm volatile("s_waitcnt vmcnt(4)" ::: "memory")
#define LGKM0 asm volatile("s_waitcnt lgkmcnt(0)" ::: "memory")
#define SB __builtin_amdgcn_sched_barrier(0)

// KSTEP: (1) LGKM0 drains last KSTEP's ds_reads (old -> ~free) so the
// re-stage DMA can't race them; (2) stage step GST (clamped) into the slot
// whose data (BMM) is already in registers; (3) vmcnt(4): the chunk read
// now (staged one KSTEP ago) has landed; (4) read next chunk -> BRD
// (consumed next KSTEP, lgkm-waited then); (5) 16 MFMA on BMM.
#define KSTEP(SS, BMM, BRD, STSLOT, RDP, GST)                                 \
  {                                                                           \
    LGKM0;                                                                    \
    SB;                                                                       \
    int gs_ = (GST) > 255 ? 255 : (GST);                                      \
    STAGE(gs_, STSLOT);                                                       \
    VM4;                                                                      \
    BRD[0] = *reinterpret_cast<const half8*>(RDP);                            \
    BRD[1] = *reinterpret_cast<const half8*>(RDP + 1024);                     \
    BRD[2] = *reinterpret_cast<const half8*>(RDP + 2048);                     \
    BRD[3] = *reinterpret_cast<const half8*>(RDP + 3072);                     \
    __builtin_amdgcn_s_setprio(1);                                            \
    _Pragma("unroll") for (int t = 0; t < 4; ++t) {                           \
      half8 as = afr[t][SS] * hb[t];                                          \
      acc[t][0] = __builtin_amdgcn_mfma_f32_16x16x32_f16(as, BMM[0], acc[t][0], 0, 0, 0); \
      acc[t][1] = __builtin_amdgcn_mfma_f32_16x16x32_f16(as, BMM[1], acc[t][1], 0, 0, 0); \
      acc[t][2] = __builtin_amdgcn_mfma_f32_16x16x32_f16(as, BMM[2], acc[t][2], 0, 0, 0); \
      acc[t][3] = __builtin_amdgcn_mfma_f32_16x16x32_f16(as, BMM[3], acc[t][3], 0, 0, 0); \
    }                                                                         \
    __builtin_amdgcn_s_setprio(0);                                            \
  }

  // prologue: stage steps 0,1; wait step 0 landed; read it into P
  STAGE(0, 0);
  STAGE(1, 1);
  VM4;
  half8 P[4], Q[4];
  P[0] = *reinterpret_cast<const half8*>(sp0);
  P[1] = *reinterpret_cast<const half8*>(sp0 + 1024);
  P[2] = *reinterpret_cast<const half8*>(sp0 + 2048);
  P[3] = *reinterpret_cast<const half8*>(sp0 + 3072);

  for (int i = 0; i < 64; ++i) {
    half8 hb[4];
#pragma unroll
    for (int t = 0; t < 4; ++t) {
      _Float16 hf = h16[i * 64 + t * 16 + l15];
      hb[t] = (half8){hf, hf, hf, hf, hf, hf, hf, hf};
    }
    int j = i * 4;
    // slots: step parity; P/Q alternate read-ahead. Invariant: entering i,
    // P = B(4i). Exit: P = B(4i+4).
    KSTEP(0, P, Q, 0, sp1, j + 2);
    KSTEP(1, Q, P, 1, sp0, j + 3);
    KSTEP(2, P, Q, 0, sp1, j + 4);
    KSTEP(3, Q, P, 1, sp0, j + 5);
  }

  // be2 contribution (exact 0 here, kept for generality): this wave owns its
  // tile's full i-range, so add sum_i h[e,i]*be2[i*64+o] once per tile.
  {
#pragma unroll
    for (int s = 0; s < 2; ++s) {
      half8 b2f[4];
#pragma unroll
      for (int c = 0; c < 4; ++c) {
        half8 v;
#pragma unroll
        for (int j = 0; j < 8; ++j)
          v[j] = (_Float16)be2[(s * 32 + quad * 8 + j) * 64 + c * 16 + l15];
        b2f[c] = v;
      }
#pragma unroll
      for (int t = 0; t < 4; ++t) {
        half8 ha;
#pragma unroll
        for (int j = 0; j < 8; ++j)
          ha[j] = h16[(s * 32 + quad * 8 + j) * 64 + t * 16 + l15];
#pragma unroll
        for (int c = 0; c < 4; ++c)
          acc[t][c] = __builtin_amdgcn_mfma_f32_16x16x32_f16(ha, b2f[c], acc[t][c], 0, 0, 0);
      }
    }
  }

  // direct scatter (no reduce): C/D layout col=lane&15, row=quad*4+reg
#pragma unroll
  for (int t = 0; t < 4; ++t) {
    int rb = t * 16 + quad * 4;
#pragma unroll
    for (int c = 0; c < 4; ++c) {
      int col = c * 16 + l15;
#pragma unroll
      for (int r = 0; r < 4; ++r) {
        int d = s_dst[rb + r];
        if (d >= 0) atomicAdd(&agg[(size_t)d * OUTD + col], acc[t][c][r]);
      }
    }
  }
}

// h_out = relu(agg + bias); re-zero agg; last step also writes fp32 d_out
__global__ void update_kernel(float* __restrict__ agg,
                              const float* __restrict__ bias,
                              float* __restrict__ hout,
                              float* __restrict__ dout, int last) {
  int g = blockIdx.x * 256 + threadIdx.x;
  if (g >= Vn * OUTD) return;
  float v = agg[g];
  agg[g] = 0.0f;
  float r = fmaxf(v + bias[g & 63], 0.0f);
  hout[g] = r;
  if (last) dout[g] = r;
}

extern "C" void kernel_launch(void* const* d_in, const int* in_sizes, int n_in,
                              void* d_out, int out_size, void* d_ws, size_t ws_size,
                              hipStream_t stream) {
  const float* node = (const float*)d_in[0];
  const float* edge = (const float*)d_in[1];
  const int* src = (const int*)d_in[2];
  const int* dst = (const int*)d_in[3];
  const float* Wp   = (const float*)d_in[4];
  const float* bp   = (const float*)d_in[5];
  const float* We1  = (const float*)d_in[6];
  const float* be1  = (const float*)d_in[7];
  const float* We2  = (const float*)d_in[8];
  const float* be2  = (const float*)d_in[9];
  const float* bias = (const float*)d_in[10];
  float* out = (float*)d_out;

  char* ws = (char*)d_ws;
  float* agg = (float*)(ws);                        // 6,400,000 B
  float* h_a = (float*)(ws + 6400000);              // 6,400,000 B
  float* h_b = (float*)(ws + 12800000);             // 6,400,000 B
  _Float16* f   = (_Float16*)(ws + 19200000);       // 25,600,000 B
  _Float16* w2s = (_Float16*)(ws + 44800000);       // 1,048,576 B

  hipMemsetAsync(agg, 0, (size_t)Vn * OUTD * sizeof(float), stream);
  proj_kernel<<<Vn, 64, 0, stream>>>(node, Wp, bp, h_a);
  edge_kernel<<<En, 128, 0, stream>>>(edge, We1, be1, f);
  w2r_kernel<<<(OUTD * OUTD * EHID) / 256, 256, 0, stream>>>(We2, w2s);

  float* hin = h_a;
  float* hout = h_b;
  for (int s = 0; s < NUM_STEPS; ++s) {
    msg_kernel<<<(En + 63) / 64, 64, 0, stream>>>(hin, f, w2s, src, dst, be2, agg);
    update_kernel<<<(Vn * OUTD + 255) / 256, 256, 0, stream>>>(
        agg, bias, hout, out, s == NUM_STEPS - 1);
    float* t = hin; hin = hout; hout = t;
  }
}